// Round 3
// baseline (281.521 us; speedup 1.0000x reference)
//
#include <hip/hip_runtime.h>

#define COLS 16384
#define TPB  256
#define NV   16        // float4 per thread (16*256*4 = 16384)
#define CAP  2048      // candidate capacity (supports k <= 2048; harness k = 256)
#define HDRW 512       // bitmap words per row (16384/32)

// ---------------- K1: per-row selection, writes header into out ----------------
// Header layout in out row (as uint32): [0,512) bitmap of accepted columns,
// [512, 512+k) accepted |x| bit patterns ordered by column rank.
__global__ __launch_bounds__(TPB, 6) void k1_select(
    const float* __restrict__ x, const int* __restrict__ kp,
    float* __restrict__ out)
{
    __shared__ unsigned       ckey[CAP];
    __shared__ unsigned short ccol[CAP];
    __shared__ unsigned       bmap[HDRW];
    __shared__ unsigned short wpfx[HDRW];
    __shared__ int      hist[256];
    __shared__ int      wsum[4];
    __shared__ unsigned s_cnt, s_minK, s_maxK;
    __shared__ int      s_bin, s_G, s_eq;

    const int tid = threadIdx.x, lane = tid & 63, wid = tid >> 6;
    const int row = blockIdx.x;
    const int kin = kp[0];
    const unsigned kk = (unsigned)(kin < 0 ? 0 : (kin > CAP ? CAP : kin));

    const float4* __restrict__ xr     = (const float4*)(x + (size_t)row * COLS);
    unsigned* __restrict__     orow_u = (unsigned*)(out + (size_t)row * COLS);

    bmap[tid] = 0; bmap[tid + 256] = 0;

    unsigned cnt = 0;
    auto compact = [&](unsigned T0) {
        if (tid == 0) { s_cnt = 0; s_minK = 0xFFFFFFFFu; s_maxK = 0u; }
        __syncthreads();
        unsigned lmin = 0xFFFFFFFFu, lmax = 0u;
        #pragma unroll
        for (int i = 0; i < NV; ++i) {
            float4 v = xr[i * TPB + tid];
            const int cb = (i * TPB + tid) * 4;
            unsigned u[4] = { __float_as_uint(v.x) & 0x7FFFFFFFu,
                              __float_as_uint(v.y) & 0x7FFFFFFFu,
                              __float_as_uint(v.z) & 0x7FFFFFFFu,
                              __float_as_uint(v.w) & 0x7FFFFFFFu };
            #pragma unroll
            for (int e = 0; e < 4; ++e) {
                const bool pred = (u[e] >= T0);
                const unsigned long long m = __ballot(pred);
                int base = 0;
                if (lane == 0 && m) base = (int)atomicAdd(&s_cnt, (unsigned)__popcll(m));
                base = __shfl(base, 0);
                if (pred) {
                    unsigned pos = (unsigned)base +
                                   (unsigned)__popcll(m & ((1ull << lane) - 1ull));
                    if (pos < CAP) { ckey[pos] = u[e]; ccol[pos] = (unsigned short)(cb + e); }
                    lmin = lmin < u[e] ? lmin : u[e];
                    lmax = lmax > u[e] ? lmax : u[e];
                }
            }
        }
        if (lmin != 0xFFFFFFFFu) { atomicMin(&s_minK, lmin); atomicMax(&s_maxK, lmax); }
        __syncthreads();
        cnt = s_cnt;
    };

    // Find T0 with kk <= cnt <= CAP. Initial guess bits(1.8f): |N(0,1)| tail
    // ~7.2% -> ~1180 candidates (binary search never triggers for normal data;
    // retries re-read from HBM/L2 on adversarial data — correctness path).
    unsigned T0 = 0x3FE66666u, lo = 0u, hi = 0x7F800001u;
    for (int it = 0; it < 40; ++it) {
        compact(T0);
        if (cnt > (unsigned)CAP)      lo = T0;
        else if (cnt < kk)            hi = T0;
        else break;
        unsigned mid = lo + ((hi - lo) >> 1);
        if (mid == lo) {                       // no window (mass ties): settle at lo, clip
            if (T0 != lo) compact(T0 = lo);
            break;
        }
        T0 = mid;
    }
    const unsigned cntc = cnt < (unsigned)CAP ? cnt : (unsigned)CAP;

    if (kk > 0) {
        unsigned T; int need, eq;
        const unsigned kmin = s_minK;              // uniform (set by last compact)
        const unsigned smax = s_maxK - kmin;
        if (smax == 0u) { T = kmin; eq = (int)cntc; need = (int)kk; }
        else {
            // Radix-select on (key - kmin): spreads digits across the fp32
            // exponent boundary (raw byte0 would be ~2 bins -> serialized atomics).
            const int topbit = 31 - __clz(smax);
            const int sh0 = topbit & ~7;           // 24-bit range -> 3 rounds
            unsigned pref = 0;
            int r = (int)kk;
            for (int sh = sh0; sh >= 0; sh -= 8) {
                hist[tid] = 0;
                __syncthreads();
                for (unsigned j = tid; j < cntc; j += TPB) {
                    unsigned sk = ckey[j] - kmin;
                    if (((unsigned long long)(sk ^ pref) >> (sh + 8)) == 0ull)
                        atomicAdd(&hist[(sk >> sh) & 255u], 1);
                }
                __syncthreads();
                int bin = 255 - tid;               // descending-bin suffix scan
                int val = hist[bin];
                int s = val;
                #pragma unroll
                for (int d = 1; d < 64; d <<= 1) { int t = __shfl_up(s, d); if (lane >= d) s += t; }
                if (lane == 63) wsum[wid] = s;
                __syncthreads();
                for (int w = 0; w < wid; ++w) s += wsum[w];
                if (s >= r && (s - val) < r) { s_bin = bin; s_G = s - val; if (sh == 0) s_eq = val; }
                __syncthreads();
                pref |= ((unsigned)s_bin) << sh;
                r -= s_G;
                __syncthreads();
            }
            T = pref + kmin; need = r; eq = s_eq;
        }

        // Mark exactly kk accepted columns in the bitmap.
        __syncthreads();
        if (eq == need) {
            for (unsigned j = tid; j < cntc; j += TPB)
                if (ckey[j] >= T) { int c = ccol[j]; atomicOr(&bmap[c >> 5], 1u << (c & 31)); }
        } else {
            // rare boundary tie: accept the `need` lowest-column equals
            for (unsigned j = tid; j < cntc; j += TPB) {
                unsigned key = ckey[j]; int c = ccol[j];
                if (key > T) atomicOr(&bmap[c >> 5], 1u << (c & 31));
                else if (key == T) {
                    int rnk = 0;
                    for (unsigned mj = 0; mj < cntc; ++mj)
                        rnk += (ckey[mj] == T && ccol[mj] < (unsigned short)c) ? 1 : 0;
                    if (rnk < need) atomicOr(&bmap[c >> 5], 1u << (c & 31));
                }
            }
        }
    }
    __syncthreads();

    // Exclusive prefix (by column) of bitmap popcounts -> rank base per word.
    int c0 = __popc(bmap[2 * tid]), c1 = __popc(bmap[2 * tid + 1]);
    int tot = c0 + c1, s2 = tot;
    #pragma unroll
    for (int d = 1; d < 64; d <<= 1) { int t = __shfl_up(s2, d); if (lane >= d) s2 += t; }
    if (lane == 63) wsum[wid] = s2;
    __syncthreads();
    int base = s2 - tot;
    for (int w = 0; w < wid; ++w) base += wsum[w];
    wpfx[2 * tid]     = (unsigned short)base;
    wpfx[2 * tid + 1] = (unsigned short)(base + c0);
    __syncthreads();

    // Header out: bitmap + rank-ordered accepted values.
    orow_u[tid]       = bmap[tid];
    orow_u[tid + 256] = bmap[tid + 256];
    if (kk > 0) {
        for (unsigned j = tid; j < cntc; j += TPB) {
            unsigned c = ccol[j], w = c >> 5, b = c & 31u;
            if ((bmap[w] >> b) & 1u) {
                int rank = (int)wpfx[w] + __popc(bmap[w] & ((1u << b) - 1u));
                orow_u[HDRW + rank] = ckey[j];
            }
        }
    }
}

// ---------------- K2: read header, compose + stream-write the row ----------------
__global__ __launch_bounds__(TPB, 8) void k2_compose(
    const int* __restrict__ kp, float* __restrict__ out)
{
    __shared__ unsigned       bmap[HDRW];
    __shared__ unsigned       sval[CAP];
    __shared__ unsigned short wpfx[HDRW];
    __shared__ int            wsum[4];

    const int tid = threadIdx.x, lane = tid & 63, wid = tid >> 6;
    const int row = blockIdx.x;
    const int kin = kp[0];
    const unsigned kk = (unsigned)(kin < 0 ? 0 : (kin > CAP ? CAP : kin));

    unsigned* __restrict__ orow_u = (unsigned*)(out + (size_t)row * COLS);
    float4* __restrict__   or4    = (float4*)(out + (size_t)row * COLS);

    bmap[tid]       = orow_u[tid];
    bmap[tid + 256] = orow_u[tid + 256];
    for (unsigned j = tid; j < kk; j += TPB) sval[j] = orow_u[HDRW + j];
    __syncthreads();

    int c0 = __popc(bmap[2 * tid]), c1 = __popc(bmap[2 * tid + 1]);
    int tot = c0 + c1, s2 = tot;
    #pragma unroll
    for (int d = 1; d < 64; d <<= 1) { int t = __shfl_up(s2, d); if (lane >= d) s2 += t; }
    if (lane == 63) wsum[wid] = s2;
    __syncthreads();
    int base = s2 - tot;
    for (int w = 0; w < wid; ++w) base += wsum[w];
    wpfx[2 * tid]     = (unsigned short)base;
    wpfx[2 * tid + 1] = (unsigned short)(base + c0);
    __syncthreads();

    #pragma unroll
    for (int i = 0; i < NV; ++i) {
        int idx4 = i * TPB + tid;
        unsigned w = bmap[idx4 >> 3];
        int sh = (idx4 & 7) * 4;
        unsigned bits = (w >> sh) & 0xFu;
        float4 o = make_float4(0.f, 0.f, 0.f, 0.f);
        if (bits) {
            int r0 = (int)wpfx[idx4 >> 3] + __popc(w & ((1u << sh) - 1u));
            if (bits & 1u) o.x = __uint_as_float(sval[r0++]);
            if (bits & 2u) o.y = __uint_as_float(sval[r0++]);
            if (bits & 4u) o.z = __uint_as_float(sval[r0++]);
            if (bits & 8u) o.w = __uint_as_float(sval[r0]);
        }
        or4[idx4] = o;
    }
}

extern "C" void kernel_launch(void* const* d_in, const int* in_sizes, int n_in,
                              void* d_out, int out_size, void* d_ws, size_t ws_size,
                              hipStream_t stream)
{
    const float* x   = (const float*)d_in[0];
    const int*   kp  = (const int*)d_in[1];
    float*       out = (float*)d_out;
    int rows = in_sizes[0] / COLS;            // 4096 for the reference shape
    k1_select <<<rows, TPB, 0, stream>>>(x, kp, out);
    k2_compose<<<rows, TPB, 0, stream>>>(kp, out);
}

// Round 4
// 121.466 us; speedup vs baseline: 2.3177x; 2.3177x over previous
//
#include <hip/hip_runtime.h>

#define COLS 16384
#define TPB  256
#define NV   16                 // uint4 per thread (16*256*4 = 16384 cols)
#define WSEG 512                // per-wave candidate segment
#define CAP  (4 * WSEG)         // 2048 total (harness k = 256)

__global__ __launch_bounds__(TPB, 4) void topk_abs_kernel(
    const float* __restrict__ x, const int* __restrict__ kp,
    float* __restrict__ out)
{
    __shared__ unsigned       ckey[CAP];        // 8 KB
    __shared__ unsigned short ccol[CAP];        // 4 KB
    __shared__ unsigned       bmap[COLS / 32];  // 2 KB
    __shared__ int            hist[256];        // 1 KB
    __shared__ int            wsum[4];
    __shared__ unsigned       wcnt[4];
    __shared__ unsigned       s_maxK;
    __shared__ int            s_bin, s_G, s_eq;

    const int tid = threadIdx.x, lane = tid & 63, wid = tid >> 6;
    const int row = blockIdx.x;
    const int kin = kp[0];
    const unsigned kk = (unsigned)(kin < 0 ? 0 : (kin > CAP ? CAP : kin));

    const uint4* __restrict__ xr  = (const uint4*)(x + (size_t)row * COLS);
    float4* __restrict__      or4 = (float4*)(out + (size_t)row * COLS);

    // ---- Entire row -> registers as |x| bit patterns (64 VGPRs). One HBM read. ----
    uint4 ub[NV];
    #pragma unroll
    for (int i = 0; i < NV; ++i) {
        uint4 t = xr[i * TPB + tid];
        t.x &= 0x7FFFFFFFu; t.y &= 0x7FFFFFFFu; t.z &= 0x7FFFFFFFu; t.w &= 0x7FFFFFFFu;
        ub[i] = t;
    }
    bmap[tid] = 0; bmap[tid + 256] = 0;

    // ---- Pass A: compact candidates >= T0 into per-wave LDS segments.
    // T0 = bits(1.8f): |N(0,1)| tail ~7.2% -> ~1180 candidates, ~295/wave
    // (13 sigma under WSEG=512). Binary-search retry re-tests REGISTERS.
    unsigned T0 = 0x3FE66666u, lo = 0u, hi = 0x7F800001u;
    unsigned seg[4] = {0, 0, 0, 0};
    unsigned cnt = 0;
    #pragma unroll 1
    for (int it = 0; it < 40; ++it) {
        if (tid < 4) wcnt[tid] = 0;
        if (tid == 0) s_maxK = 0u;
        __syncthreads();
        unsigned lmax = 0u;
        #pragma unroll
        for (int i = 0; i < NV; ++i) {
            const int cb = (i * TPB + tid) * 4;
            const unsigned u0 = ub[i].x, u1 = ub[i].y, u2 = ub[i].z, u3 = ub[i].w;
            if (u0 >= T0) { unsigned p = atomicAdd(&wcnt[wid], 1u); if (p < WSEG) { ckey[wid * WSEG + p] = u0; ccol[wid * WSEG + p] = (unsigned short)(cb + 0); } lmax = max(lmax, u0); }
            if (u1 >= T0) { unsigned p = atomicAdd(&wcnt[wid], 1u); if (p < WSEG) { ckey[wid * WSEG + p] = u1; ccol[wid * WSEG + p] = (unsigned short)(cb + 1); } lmax = max(lmax, u1); }
            if (u2 >= T0) { unsigned p = atomicAdd(&wcnt[wid], 1u); if (p < WSEG) { ckey[wid * WSEG + p] = u2; ccol[wid * WSEG + p] = (unsigned short)(cb + 2); } lmax = max(lmax, u2); }
            if (u3 >= T0) { unsigned p = atomicAdd(&wcnt[wid], 1u); if (p < WSEG) { ckey[wid * WSEG + p] = u3; ccol[wid * WSEG + p] = (unsigned short)(cb + 3); } lmax = max(lmax, u3); }
        }
        if (lmax) atomicMax(&s_maxK, lmax);
        __syncthreads();
        const unsigned w0 = wcnt[0], w1 = wcnt[1], w2 = wcnt[2], w3 = wcnt[3];
        const bool ovf = (w0 > WSEG) | (w1 > WSEG) | (w2 > WSEG) | (w3 > WSEG);
        seg[0] = min(w0, (unsigned)WSEG); seg[1] = min(w1, (unsigned)WSEG);
        seg[2] = min(w2, (unsigned)WSEG); seg[3] = min(w3, (unsigned)WSEG);
        cnt = seg[0] + seg[1] + seg[2] + seg[3];
        if (!ovf && cnt >= kk) break;        // uniform exit (normal data: iter 0)
        if (ovf) lo = T0; else hi = T0;
        const unsigned mid = lo + ((hi - lo) >> 1);
        if (mid == T0) break;                // settled at lo (mass ties): clipped
        T0 = mid;
        __syncthreads();                     // all read wcnt before next reset
    }

    if (kk > 0 && cnt > 0) {
        // ---- Pass B: exact radix-select on (key - T0); adaptive first digit
        // avoids the fp32-exponent-boundary bin degeneracy. ----
        unsigned T; int need, eq;
        const unsigned kmin = T0;            // all stored keys >= T0
        const unsigned smax = s_maxK - kmin;
        if (smax == 0u) { T = kmin; eq = (int)cnt; need = (int)kk; }
        else {
            const int sh0 = (31 - __clz(smax)) & ~7;
            unsigned pref = 0;
            int r = (int)kk;
            for (int sh = sh0; sh >= 0; sh -= 8) {
                hist[tid] = 0;
                __syncthreads();
                #pragma unroll
                for (int w = 0; w < 4; ++w)
                    for (unsigned j = tid; j < seg[w]; j += TPB) {
                        unsigned sk = ckey[w * WSEG + j] - kmin;
                        if (((unsigned long long)(sk ^ pref) >> (sh + 8)) == 0ull)
                            atomicAdd(&hist[(sk >> sh) & 255u], 1);
                    }
                __syncthreads();
                int bin = 255 - tid;         // descending-bin suffix scan
                int val = hist[bin];
                int s = val;
                #pragma unroll
                for (int d = 1; d < 64; d <<= 1) { int t = __shfl_up(s, d); if (lane >= d) s += t; }
                if (lane == 63) wsum[wid] = s;
                __syncthreads();
                for (int w = 0; w < wid; ++w) s += wsum[w];
                if (s >= r && (s - val) < r) { s_bin = bin; s_G = s - val; if (sh == 0) s_eq = val; }
                __syncthreads();
                pref |= ((unsigned)s_bin) << sh;
                r -= s_G;
                __syncthreads();
            }
            T = pref + kmin; need = r; eq = s_eq;
        }

        // ---- Mark exactly kk accepted columns in the bitmap. ----
        if (eq == need) {
            #pragma unroll
            for (int w = 0; w < 4; ++w)
                for (unsigned j = tid; j < seg[w]; j += TPB) {
                    unsigned idx = w * WSEG + j;
                    if (ckey[idx] >= T) { int c = ccol[idx]; atomicOr(&bmap[c >> 5], 1u << (c & 31)); }
                }
        } else {
            // rare exact-tie at boundary: accept the `need` lowest-column equals
            #pragma unroll
            for (int w = 0; w < 4; ++w)
                for (unsigned j = tid; j < seg[w]; j += TPB) {
                    unsigned idx = w * WSEG + j;
                    unsigned key = ckey[idx]; unsigned short c = ccol[idx];
                    if (key > T) atomicOr(&bmap[c >> 5], 1u << (c & 31));
                    else if (key == T) {
                        int rnk = 0;
                        #pragma unroll
                        for (int w2 = 0; w2 < 4; ++w2)
                            for (unsigned j2 = 0; j2 < seg[w2]; ++j2) {
                                unsigned i2 = w2 * WSEG + j2;
                                rnk += (ckey[i2] == T && ccol[i2] < c) ? 1 : 0;
                            }
                        if (rnk < need) atomicOr(&bmap[c >> 5], 1u << (c & 31));
                    }
                }
        }
    }
    __syncthreads();

    // ---- Pass C: compose output from registers + bitmap; write-only stream. ----
    #pragma unroll
    for (int i = 0; i < NV; ++i) {
        int idx4 = i * TPB + tid;
        unsigned w = bmap[idx4 >> 3];            // 8 lanes/word -> LDS broadcast
        unsigned b = (w >> ((idx4 & 7) * 4)) & 0xFu;
        float4 o;
        o.x = (b & 1u) ? __uint_as_float(ub[i].x) : 0.f;
        o.y = (b & 2u) ? __uint_as_float(ub[i].y) : 0.f;
        o.z = (b & 4u) ? __uint_as_float(ub[i].z) : 0.f;
        o.w = (b & 8u) ? __uint_as_float(ub[i].w) : 0.f;
        or4[idx4] = o;
    }
}

extern "C" void kernel_launch(void* const* d_in, const int* in_sizes, int n_in,
                              void* d_out, int out_size, void* d_ws, size_t ws_size,
                              hipStream_t stream)
{
    const float* x   = (const float*)d_in[0];
    const int*   kp  = (const int*)d_in[1];
    float*       out = (float*)d_out;
    int rows = in_sizes[0] / COLS;            // 4096 for the reference shape
    topk_abs_kernel<<<rows, TPB, 0, stream>>>(x, kp, out);
}

// Round 5
// 117.788 us; speedup vs baseline: 2.3901x; 1.0312x over previous
//
#include <hip/hip_runtime.h>

#define COLS 16384
#define TPB  256
#define NV   16                 // uint4 per thread (16*256*4 = 16384 cols)

__global__ __launch_bounds__(TPB, 4) void topk_abs_kernel(
    const float* __restrict__ x, const int* __restrict__ kp,
    float* __restrict__ out)
{
    __shared__ unsigned bmap[COLS / 32];   // 2 KB accepted-column bitmap
    __shared__ int      hist[256];         // 1 KB
    __shared__ int      wsum[4];
    __shared__ unsigned s_cnt;
    __shared__ unsigned s_max;
    __shared__ int      s_bin, s_G, s_eq;

    const int tid = threadIdx.x, lane = tid & 63, wid = tid >> 6;
    const int row = blockIdx.x;
    const int kin = kp[0];
    const unsigned kk = (unsigned)(kin < 0 ? 0 : (kin > COLS ? COLS : kin));

    const uint4* __restrict__ xr  = (const uint4*)(x + (size_t)row * COLS);
    float4* __restrict__      or4 = (float4*)(out + (size_t)row * COLS);

    // ---- Entire row -> registers as |x| bit patterns. One HBM read, ever. ----
    uint4 ub[NV];
    #pragma unroll
    for (int i = 0; i < NV; ++i) {
        uint4 t = xr[i * TPB + tid];
        t.x &= 0x7FFFFFFFu; t.y &= 0x7FFFFFFFu; t.z &= 0x7FFFFFFFu; t.w &= 0x7FFFFFFFu;
        ub[i] = t;
    }

    bmap[tid] = 0; bmap[tid + 256] = 0;
    if (tid == 0) s_max = 0u;
    __syncthreads();

    // ---- Row max (for adaptive radix digit) ----
    unsigned lmax = 0u;
    #pragma unroll
    for (int i = 0; i < NV; ++i)
        lmax = max(lmax, max(max(ub[i].x, ub[i].y), max(ub[i].z, ub[i].w)));
    #pragma unroll
    for (int d = 32; d; d >>= 1) lmax = max(lmax, (unsigned)__shfl_xor((int)lmax, d));
    if (lane == 0) atomicMax(&s_max, lmax);
    __syncthreads();
    const unsigned smax = s_max;

    // ---- Register-direct count(>= T). 64 predicated adds + wave reduce. ----
    auto count_ge = [&](unsigned T) -> unsigned {
        __syncthreads();                       // prior s_cnt readers done
        if (tid == 0) s_cnt = 0;
        __syncthreads();
        int c = 0;
        #pragma unroll
        for (int i = 0; i < NV; ++i)
            c += (ub[i].x >= T) + (ub[i].y >= T) + (ub[i].z >= T) + (ub[i].w >= T);
        #pragma unroll
        for (int d = 32; d; d >>= 1) c += __shfl_xor(c, d);
        if (lane == 0) atomicAdd(&s_cnt, (unsigned)c);
        __syncthreads();
        return s_cnt;                          // uniform
    };

    // T0 = bits(1.8f): |N(0,1)| tail ~7.2% -> ~1180 candidates >= T0.
    // If too few (adversarial data), bit-space bisection to the LARGEST T0
    // with count >= kk (exact, no overshoot). Register-only, no re-reads.
    unsigned T0 = 0x3FE66666u;
    unsigned cnt = count_ge(T0);
    if (kk > 0 && cnt < kk) {
        unsigned lo = 0u, hi = T0;             // cnt(0)=COLS>=kk, cnt(hi)<kk
        while (hi - lo > 1u) {
            unsigned mid = lo + ((hi - lo) >> 1);
            unsigned c = count_ge(mid);
            if (c >= kk) lo = mid; else hi = mid;
        }
        T0 = lo;
        cnt = count_ge(T0);
    }

    if (kk > 0) {
        unsigned T; int need, eq;
        if (cnt == kk)        { T = T0; need = 0; eq = 0; }            // accept all >= T0
        else if (smax == T0)  { T = T0; eq = (int)cnt; need = (int)kk; } // mass tie at T0
        else {
            // ---- Exact radix-select directly from registers.
            // Window [A, A+W); digit (u-A)>>sh; sh0 = topbit-7 guarantees
            // >=128 occupied bins (no fp32-exponent degeneracy). ----
            const unsigned range = smax - T0;
            const int topbit = 31 - __clz(range);
            int sh = topbit - 7; if (sh < 0) sh = 0;
            unsigned A = T0;
            unsigned W = (topbit >= 31) ? 0xFFFFFFFFu : (1u << (topbit + 1));
            int r = (int)kk;
            for (;;) {
                hist[tid] = 0;
                __syncthreads();
                #pragma unroll
                for (int i = 0; i < NV; ++i) {
                    const unsigned u0 = ub[i].x, u1 = ub[i].y, u2 = ub[i].z, u3 = ub[i].w;
                    if (u0 >= A && (u0 - A) < W) atomicAdd(&hist[(u0 - A) >> sh], 1);
                    if (u1 >= A && (u1 - A) < W) atomicAdd(&hist[(u1 - A) >> sh], 1);
                    if (u2 >= A && (u2 - A) < W) atomicAdd(&hist[(u2 - A) >> sh], 1);
                    if (u3 >= A && (u3 - A) < W) atomicAdd(&hist[(u3 - A) >> sh], 1);
                }
                __syncthreads();
                int bin = 255 - tid;           // descending-bin suffix scan
                int val = hist[bin];
                int s = val;
                #pragma unroll
                for (int d = 1; d < 64; d <<= 1) { int t = __shfl_up(s, d); if (lane >= d) s += t; }
                if (lane == 63) wsum[wid] = s;
                __syncthreads();
                for (int w = 0; w < wid; ++w) s += wsum[w];
                if (s >= r && (s - val) < r) { s_bin = bin; s_G = s - val; if (sh == 0) s_eq = val; }
                __syncthreads();
                A += ((unsigned)s_bin) << sh;
                W = 1u << sh;                  // next window = winning bin
                r -= s_G;
                if (sh == 0) break;
                sh = (sh >= 8) ? sh - 8 : 0;
                __syncthreads();               // protect hist/s_bin before reuse
            }
            T = A; need = r; eq = s_eq;
        }

        // ---- Mark accepted columns in bitmap, straight from registers. ----
        if (eq == need) {
            #pragma unroll
            for (int i = 0; i < NV; ++i) {
                const int cb = (i * TPB + tid) * 4;
                if (ub[i].x >= T) atomicOr(&bmap[(cb + 0) >> 5], 1u << ((cb + 0) & 31));
                if (ub[i].y >= T) atomicOr(&bmap[(cb + 1) >> 5], 1u << ((cb + 1) & 31));
                if (ub[i].z >= T) atomicOr(&bmap[(cb + 2) >> 5], 1u << ((cb + 2) & 31));
                if (ub[i].w >= T) atomicOr(&bmap[(cb + 3) >> 5], 1u << ((cb + 3) & 31));
            }
        } else {
            // Rare boundary tie: among u==T accept the `need` lowest columns.
            // Binary-search the cutoff column; counts are register-direct.
            unsigned loC = 0, hiC = COLS - 1;
            if (need > 0) {
                while (loC < hiC) {
                    unsigned mid = (loC + hiC) >> 1;
                    __syncthreads();
                    if (tid == 0) s_cnt = 0;
                    __syncthreads();
                    int c = 0;
                    #pragma unroll
                    for (int i = 0; i < NV; ++i) {
                        const unsigned cb = (unsigned)(i * TPB + tid) * 4u;
                        c += (ub[i].x == T && (cb + 0) <= mid);
                        c += (ub[i].y == T && (cb + 1) <= mid);
                        c += (ub[i].z == T && (cb + 2) <= mid);
                        c += (ub[i].w == T && (cb + 3) <= mid);
                    }
                    #pragma unroll
                    for (int d = 32; d; d >>= 1) c += __shfl_xor(c, d);
                    if (lane == 0) atomicAdd(&s_cnt, (unsigned)c);
                    __syncthreads();
                    if (s_cnt >= (unsigned)need) hiC = mid; else loC = mid + 1;
                }
            }
            const unsigned cstar = loC;
            const bool take_eq = (need > 0);
            #pragma unroll
            for (int i = 0; i < NV; ++i) {
                const unsigned cb = (unsigned)(i * TPB + tid) * 4u;
                const unsigned u0 = ub[i].x, u1 = ub[i].y, u2 = ub[i].z, u3 = ub[i].w;
                if (u0 > T || (take_eq && u0 == T && (cb + 0) <= cstar)) atomicOr(&bmap[(cb + 0) >> 5], 1u << ((cb + 0) & 31));
                if (u1 > T || (take_eq && u1 == T && (cb + 1) <= cstar)) atomicOr(&bmap[(cb + 1) >> 5], 1u << ((cb + 1) & 31));
                if (u2 > T || (take_eq && u2 == T && (cb + 2) <= cstar)) atomicOr(&bmap[(cb + 2) >> 5], 1u << ((cb + 2) & 31));
                if (u3 > T || (take_eq && u3 == T && (cb + 3) <= cstar)) atomicOr(&bmap[(cb + 3) >> 5], 1u << ((cb + 3) & 31));
            }
        }
    }
    __syncthreads();

    // ---- Compose output from registers + bitmap; write-only stream. ----
    #pragma unroll
    for (int i = 0; i < NV; ++i) {
        int idx4 = i * TPB + tid;
        unsigned w = bmap[idx4 >> 3];          // 8 lanes/word -> LDS broadcast
        unsigned b = (w >> ((idx4 & 7) * 4)) & 0xFu;
        float4 o;
        o.x = (b & 1u) ? __uint_as_float(ub[i].x) : 0.f;
        o.y = (b & 2u) ? __uint_as_float(ub[i].y) : 0.f;
        o.z = (b & 4u) ? __uint_as_float(ub[i].z) : 0.f;
        o.w = (b & 8u) ? __uint_as_float(ub[i].w) : 0.f;
        or4[idx4] = o;
    }
}

extern "C" void kernel_launch(void* const* d_in, const int* in_sizes, int n_in,
                              void* d_out, int out_size, void* d_ws, size_t ws_size,
                              hipStream_t stream)
{
    const float* x   = (const float*)d_in[0];
    const int*   kp  = (const int*)d_in[1];
    float*       out = (float*)d_out;
    int rows = in_sizes[0] / COLS;             // 4096 for the reference shape
    topk_abs_kernel<<<rows, TPB, 0, stream>>>(x, kp, out);
}

// Round 7
// 108.258 us; speedup vs baseline: 2.6005x; 1.0880x over previous
//
#include <hip/hip_runtime.h>

#define COLS 16384
#define TPB  512
#define NV   8                  // 4-wide vec per thread (8*512*4 = 16384 cols)
#define NW   (TPB / 64)         // 8 waves

typedef unsigned uvec4 __attribute__((ext_vector_type(4)));
typedef float    fvec4 __attribute__((ext_vector_type(4)));

__global__ __launch_bounds__(TPB, 6) void topk_abs_kernel(
    const float* __restrict__ x, const int* __restrict__ kp,
    float* __restrict__ out)
{
    __shared__ unsigned bmap[COLS / 32];   // 2 KB accepted-column bitmap
    __shared__ int      hist[256];         // 1 KB
    __shared__ int      wsum[NW];
    __shared__ unsigned s_cnt;
    __shared__ unsigned s_max;
    __shared__ int      s_bin, s_G, s_eq;

    const int tid = threadIdx.x, lane = tid & 63, wid = tid >> 6;
    const int row = blockIdx.x;
    const int kin = kp[0];
    const unsigned kk = (unsigned)(kin < 0 ? 0 : (kin > COLS ? COLS : kin));

    const uvec4* __restrict__ xr  = (const uvec4*)(x + (size_t)row * COLS);
    fvec4* __restrict__       or4 = (fvec4*)(out + (size_t)row * COLS);

    if (tid == 0) s_max = 0u;
    bmap[tid] = 0;                          // 512 words, one per thread
    __syncthreads();                        // also orders s_max init

    // ---- Row -> registers as |x| bits; fold in row-max. One HBM read, ever. ----
    uvec4 ub[NV];
    unsigned lmax = 0u;
    #pragma unroll
    for (int i = 0; i < NV; ++i) {
        uvec4 t = __builtin_nontemporal_load(&xr[i * TPB + tid]);
        t &= 0x7FFFFFFFu;
        ub[i] = t;
        lmax = max(lmax, max(max(t.x, t.y), max(t.z, t.w)));
    }
    #pragma unroll
    for (int d = 32; d; d >>= 1) lmax = max(lmax, (unsigned)__shfl_xor((int)lmax, d));
    if (lane == 0) atomicMax(&s_max, lmax);
    __syncthreads();
    const unsigned smax = s_max;

    // ---- Register-direct count(>= T): 32 predicated adds + wave reduce. ----
    auto count_ge = [&](unsigned T) -> unsigned {
        __syncthreads();                    // prior s_cnt readers done
        if (tid == 0) s_cnt = 0;
        __syncthreads();
        int c = 0;
        #pragma unroll
        for (int i = 0; i < NV; ++i)
            c += (ub[i].x >= T) + (ub[i].y >= T) + (ub[i].z >= T) + (ub[i].w >= T);
        #pragma unroll
        for (int d = 32; d; d >>= 1) c += __shfl_xor(c, d);
        if (lane == 0) atomicAdd(&s_cnt, (unsigned)c);
        __syncthreads();
        return s_cnt;                       // uniform
    };

    // T0 = bits(1.8f): |N(0,1)| tail ~7.2% -> ~1180 candidates >= T0.
    // Adversarial data: bisect to the LARGEST T0 with count >= kk (register-only).
    unsigned T0 = 0x3FE66666u;
    unsigned cnt = count_ge(T0);
    if (kk > 0 && cnt < kk) {
        unsigned lo = 0u, hi = T0;
        while (hi - lo > 1u) {
            unsigned mid = lo + ((hi - lo) >> 1);
            unsigned c = count_ge(mid);
            if (c >= kk) lo = mid; else hi = mid;
        }
        T0 = lo;
        cnt = count_ge(T0);
    }

    if (kk > 0) {
        unsigned T; int need, eq;
        if (cnt == kk)       { T = T0; need = 0; eq = 0; }              // accept all >= T0
        else if (smax == T0) { T = T0; eq = (int)cnt; need = (int)kk; } // mass tie at T0
        else {
            // ---- Exact radix-select from registers. Window [A, A+W), digit
            // (u-A)>>sh; sh0 = topbit-7 -> >=128 occupied bins (no fp32
            // exponent-boundary degeneracy). ----
            const unsigned range = smax - T0;
            const int topbit = 31 - __clz(range);
            int sh = topbit - 7; if (sh < 0) sh = 0;
            unsigned A = T0;
            unsigned W = (topbit >= 31) ? 0xFFFFFFFFu : (1u << (topbit + 1));
            int r = (int)kk;
            for (;;) {
                if (tid < 256) hist[tid] = 0;
                __syncthreads();                               // B1
                #pragma unroll
                for (int i = 0; i < NV; ++i) {
                    const unsigned u0 = ub[i].x, u1 = ub[i].y, u2 = ub[i].z, u3 = ub[i].w;
                    if (u0 >= A && (u0 - A) < W) atomicAdd(&hist[(u0 - A) >> sh], 1);
                    if (u1 >= A && (u1 - A) < W) atomicAdd(&hist[(u1 - A) >> sh], 1);
                    if (u2 >= A && (u2 - A) < W) atomicAdd(&hist[(u2 - A) >> sh], 1);
                    if (u3 >= A && (u3 - A) < W) atomicAdd(&hist[(u3 - A) >> sh], 1);
                }
                __syncthreads();                               // B2
                int bin = 0, val = 0, s = 0;
                if (tid < 256) {                               // waves 0-3 scan
                    bin = 255 - tid;                           // descending bins
                    val = hist[bin];
                    s = val;
                    #pragma unroll
                    for (int d = 1; d < 64; d <<= 1) { int t = __shfl_up(s, d); if (lane >= d) s += t; }
                    if (lane == 63) wsum[wid] = s;
                }
                __syncthreads();                               // B3
                if (tid < 256) {
                    for (int w = 0; w < wid; ++w) s += wsum[w];
                    if (s >= r && (s - val) < r) { s_bin = bin; s_G = s - val; if (sh == 0) s_eq = val; }
                }
                __syncthreads();                               // B4
                A += ((unsigned)s_bin) << sh;
                W = 1u << sh;
                r -= s_G;
                if (sh == 0) break;
                sh = (sh >= 8) ? sh - 8 : 0;
            }
            T = A; need = r; eq = s_eq;
        }

        // ---- Mark accepted columns in bitmap, straight from registers. ----
        if (eq == need) {
            #pragma unroll
            for (int i = 0; i < NV; ++i) {
                const int cb = (i * TPB + tid) * 4;
                if (ub[i].x >= T) atomicOr(&bmap[(cb + 0) >> 5], 1u << ((cb + 0) & 31));
                if (ub[i].y >= T) atomicOr(&bmap[(cb + 1) >> 5], 1u << ((cb + 1) & 31));
                if (ub[i].z >= T) atomicOr(&bmap[(cb + 2) >> 5], 1u << ((cb + 2) & 31));
                if (ub[i].w >= T) atomicOr(&bmap[(cb + 3) >> 5], 1u << ((cb + 3) & 31));
            }
        } else {
            // Rare boundary tie: among u==T accept the `need` lowest columns.
            unsigned loC = 0, hiC = COLS - 1;
            if (need > 0) {
                while (loC < hiC) {
                    unsigned mid = (loC + hiC) >> 1;
                    __syncthreads();
                    if (tid == 0) s_cnt = 0;
                    __syncthreads();
                    int c = 0;
                    #pragma unroll
                    for (int i = 0; i < NV; ++i) {
                        const unsigned cb = (unsigned)(i * TPB + tid) * 4u;
                        c += (ub[i].x == T && (cb + 0) <= mid);
                        c += (ub[i].y == T && (cb + 1) <= mid);
                        c += (ub[i].z == T && (cb + 2) <= mid);
                        c += (ub[i].w == T && (cb + 3) <= mid);
                    }
                    #pragma unroll
                    for (int d = 32; d; d >>= 1) c += __shfl_xor(c, d);
                    if (lane == 0) atomicAdd(&s_cnt, (unsigned)c);
                    __syncthreads();
                    if (s_cnt >= (unsigned)need) hiC = mid; else loC = mid + 1;
                }
            }
            const unsigned cstar = loC;
            const bool take_eq = (need > 0);
            #pragma unroll
            for (int i = 0; i < NV; ++i) {
                const unsigned cb = (unsigned)(i * TPB + tid) * 4u;
                const unsigned u0 = ub[i].x, u1 = ub[i].y, u2 = ub[i].z, u3 = ub[i].w;
                if (u0 > T || (take_eq && u0 == T && (cb + 0) <= cstar)) atomicOr(&bmap[(cb + 0) >> 5], 1u << ((cb + 0) & 31));
                if (u1 > T || (take_eq && u1 == T && (cb + 1) <= cstar)) atomicOr(&bmap[(cb + 1) >> 5], 1u << ((cb + 1) & 31));
                if (u2 > T || (take_eq && u2 == T && (cb + 2) <= cstar)) atomicOr(&bmap[(cb + 2) >> 5], 1u << ((cb + 2) & 31));
                if (u3 > T || (take_eq && u3 == T && (cb + 3) <= cstar)) atomicOr(&bmap[(cb + 3) >> 5], 1u << ((cb + 3) & 31));
            }
        }
    }
    __syncthreads();

    // ---- Compose output from registers + bitmap; non-temporal write stream. ----
    #pragma unroll
    for (int i = 0; i < NV; ++i) {
        int idx4 = i * TPB + tid;
        unsigned w = bmap[idx4 >> 3];          // 8 lanes/word -> LDS broadcast
        unsigned b = (w >> ((idx4 & 7) * 4)) & 0xFu;
        fvec4 o;
        o.x = (b & 1u) ? __uint_as_float(ub[i].x) : 0.f;
        o.y = (b & 2u) ? __uint_as_float(ub[i].y) : 0.f;
        o.z = (b & 4u) ? __uint_as_float(ub[i].z) : 0.f;
        o.w = (b & 8u) ? __uint_as_float(ub[i].w) : 0.f;
        __builtin_nontemporal_store(o, &or4[idx4]);
    }
}

extern "C" void kernel_launch(void* const* d_in, const int* in_sizes, int n_in,
                              void* d_out, int out_size, void* d_ws, size_t ws_size,
                              hipStream_t stream)
{
    const float* x   = (const float*)d_in[0];
    const int*   kp  = (const int*)d_in[1];
    float*       out = (float*)d_out;
    int rows = in_sizes[0] / COLS;             // 4096 for the reference shape
    topk_abs_kernel<<<rows, TPB, 0, stream>>>(x, kp, out);
}

// Round 8
// 104.224 us; speedup vs baseline: 2.7011x; 1.0387x over previous
//
#include <hip/hip_runtime.h>

#define COLS 16384
#define TPB  512
#define NV   8                   // vec4 per thread (8*512*4 = 16384 cols)
#define NW   (TPB / 64)          // 8 waves
#define NBIN 4096
#define CHK  (NBIN / TPB)        // 8 bins per thread in the scan
#define SH1  12

typedef unsigned uvec4 __attribute__((ext_vector_type(4)));
typedef float    fvec4 __attribute__((ext_vector_type(4)));

__global__ __launch_bounds__(TPB, 6) void topk_abs_kernel(
    const float* __restrict__ x, const int* __restrict__ kp,
    float* __restrict__ out)
{
    __shared__ int      hist[NBIN];     // 16 KB (fallback radix reuses [0,256))
    __shared__ int      wsum[NW];
    __shared__ unsigned s_cnt, s_max, s_total;
    __shared__ int      s_bin, s_G, s_eq;

    const int tid = threadIdx.x, lane = tid & 63, wid = tid >> 6;
    const int row = blockIdx.x;
    const int kin = kp[0];
    const unsigned kk = (unsigned)(kin < 0 ? 0 : (kin > COLS ? COLS : kin));

    const uvec4* __restrict__ xr  = (const uvec4*)(x + (size_t)row * COLS);
    fvec4* __restrict__       or4 = (fvec4*)(out + (size_t)row * COLS);

    // ---- Issue the row's 8 non-temporal loads; zero hist under their latency ----
    uvec4 ub[NV];
    #pragma unroll
    for (int i = 0; i < NV; ++i) ub[i] = __builtin_nontemporal_load(&xr[i * TPB + tid]);
    #pragma unroll
    for (int j = 0; j < CHK; ++j) hist[tid + j * TPB] = 0;
    __syncthreads();

    // ---- Pass 1: |x| mask + FIXED-bin histogram (u - T0) >> 12, clamp to 4095.
    // Bins cover |x| in [1.8, 7.2); N(0,1) tail past T0 ~7.2% -> ~1180 counts. ----
    const unsigned T0 = 0x3FE66666u;    // bits(1.8f)
    #pragma unroll
    for (int i = 0; i < NV; ++i) {
        uvec4 t = ub[i] & 0x7FFFFFFFu;
        ub[i] = t;
        #define H1(u) { if ((u) >= T0) { unsigned b = ((u) - T0) >> SH1; \
                        b = b < (NBIN - 1) ? b : (NBIN - 1); atomicAdd(&hist[b], 1); } }
        H1(t.x) H1(t.y) H1(t.z) H1(t.w)
        #undef H1
    }
    __syncthreads();

    // ---- Descending suffix-scan over hist + crossing pick (both rounds) ----
    auto scan_pick = [&](int rank) {
        const int c  = (TPB - 1) - tid;          // tid 0 owns the TOP chunk
        const int b0 = c * CHK;
        int S = 0;
        #pragma unroll
        for (int j = 0; j < CHK; ++j) S += hist[b0 + j];
        int P = S;
        #pragma unroll
        for (int d = 1; d < 64; d <<= 1) { int t = __shfl_up(P, d); if (lane >= d) P += t; }
        if (lane == 63) wsum[wid] = P;
        __syncthreads();
        for (int w = 0; w < wid; ++w) P += wsum[w];
        const int above = P - S;                 // count strictly above this chunk
        if (P >= rank && above < rank) {         // unique crossing chunk
            int cum = above;
            #pragma unroll
            for (int j = CHK - 1; j >= 0; --j) {
                int h = hist[b0 + j], prev = cum;
                cum += h;
                if (cum >= rank && prev < rank) { s_bin = b0 + j; s_G = prev; s_eq = h; }
            }
        }
        if (tid == TPB - 1) s_total = (unsigned)P;   // chunk 0 inclusive = total
        __syncthreads();
    };

    unsigned T = 0xFFFFFFFFu;                    // kk==0 -> accept nothing
    int need = 0, eq = 0;
    if (kk > 0) {
        scan_pick((int)kk);
        const unsigned cnt = s_total;
        const int B1 = s_bin, G1 = s_G;          // valid iff cnt >= kk
        bool handled = false;
        if (cnt == kk) { T = T0; need = 0; eq = 0; handled = true; }
        else if (cnt > kk && B1 < NBIN - 1) {
            // ---- Pass 2: exact select inside bin B1 (window = 4096 key values) ----
            const unsigned A1 = T0 + ((unsigned)B1 << SH1);
            const int r1 = (int)kk - G1;
            #pragma unroll
            for (int j = 0; j < CHK; ++j) hist[tid + j * TPB] = 0;
            __syncthreads();
            #pragma unroll
            for (int i = 0; i < NV; ++i) {
                #define H2(u) { unsigned d = (u) - A1; if (d < (unsigned)NBIN) atomicAdd(&hist[d], 1); }
                H2(ub[i].x) H2(ub[i].y) H2(ub[i].z) H2(ub[i].w)
                #undef H2
            }
            __syncthreads();
            scan_pick(r1);
            T = A1 + (unsigned)s_bin; need = r1 - s_G; eq = s_eq;
            handled = true;
        }
        if (!handled) {
            // ---- Rare fallback (cnt < kk, or boundary in clamp bin): proven
            // round-7 path — bisection + adaptive 256-bin radix from registers. ----
            if (tid == 0) s_max = 0u;
            __syncthreads();
            unsigned lmax = 0u;
            #pragma unroll
            for (int i = 0; i < NV; ++i)
                lmax = max(lmax, max(max(ub[i].x, ub[i].y), max(ub[i].z, ub[i].w)));
            #pragma unroll
            for (int d = 32; d; d >>= 1) lmax = max(lmax, (unsigned)__shfl_xor((int)lmax, d));
            if (lane == 0) atomicMax(&s_max, lmax);
            __syncthreads();
            const unsigned smax = s_max;

            auto count_ge = [&](unsigned Tq) -> unsigned {
                __syncthreads();
                if (tid == 0) s_cnt = 0;
                __syncthreads();
                int c = 0;
                #pragma unroll
                for (int i = 0; i < NV; ++i)
                    c += (ub[i].x >= Tq) + (ub[i].y >= Tq) + (ub[i].z >= Tq) + (ub[i].w >= Tq);
                #pragma unroll
                for (int d = 32; d; d >>= 1) c += __shfl_xor(c, d);
                if (lane == 0) atomicAdd(&s_cnt, (unsigned)c);
                __syncthreads();
                return s_cnt;
            };

            unsigned T0f = T0, cntf = cnt;
            if (cntf < kk) {                     // lower the threshold exactly
                unsigned lo = 0u, hi = T0;
                while (hi - lo > 1u) {
                    unsigned mid = lo + ((hi - lo) >> 1);
                    if (count_ge(mid) >= kk) lo = mid; else hi = mid;
                }
                T0f = lo;
                cntf = count_ge(T0f);
            }
            if (cntf == kk)       { T = T0f; need = 0; eq = 0; }
            else if (smax == T0f) { T = T0f; eq = (int)cntf; need = (int)kk; }
            else {
                const unsigned range = smax - T0f;
                const int topbit = 31 - __clz(range);
                int sh = topbit - 7; if (sh < 0) sh = 0;
                unsigned A = T0f;
                unsigned W = (topbit >= 31) ? 0xFFFFFFFFu : (1u << (topbit + 1));
                int r = (int)kk;
                for (;;) {
                    if (tid < 256) hist[tid] = 0;
                    __syncthreads();
                    #pragma unroll
                    for (int i = 0; i < NV; ++i) {
                        #define HR(u) { if ((u) >= A && ((u) - A) < W) atomicAdd(&hist[((u) - A) >> sh], 1); }
                        HR(ub[i].x) HR(ub[i].y) HR(ub[i].z) HR(ub[i].w)
                        #undef HR
                    }
                    __syncthreads();
                    int bin = 0, val = 0, s = 0;
                    if (tid < 256) {
                        bin = 255 - tid;
                        val = hist[bin];
                        s = val;
                        #pragma unroll
                        for (int d = 1; d < 64; d <<= 1) { int t = __shfl_up(s, d); if (lane >= d) s += t; }
                        if (lane == 63) wsum[wid] = s;
                    }
                    __syncthreads();
                    if (tid < 256) {
                        for (int w = 0; w < wid; ++w) s += wsum[w];
                        if (s >= r && (s - val) < r) { s_bin = bin; s_G = s - val; if (sh == 0) s_eq = val; }
                    }
                    __syncthreads();
                    A += ((unsigned)s_bin) << sh;
                    W = 1u << sh;
                    r -= s_G;
                    if (sh == 0) break;
                    sh = (sh >= 8) ? sh - 8 : 0;
                }
                T = A; need = r; eq = s_eq;
            }
        }
    }

    // ---- Boundary tie (need != eq): among u==T accept the `need` lowest
    // columns; bisect the cutoff column with register-direct counts. ----
    unsigned cstar = COLS - 1;                   // default: accept all equals
    if (kk > 0 && need != eq) {
        unsigned loC = 0, hiC = COLS - 1;
        while (loC < hiC) {
            unsigned mid = (loC + hiC) >> 1;
            __syncthreads();
            if (tid == 0) s_cnt = 0;
            __syncthreads();
            int c = 0;
            #pragma unroll
            for (int i = 0; i < NV; ++i) {
                const unsigned cb = (unsigned)(i * TPB + tid) * 4u;
                c += (ub[i].x == T && (cb + 0) <= mid);
                c += (ub[i].y == T && (cb + 1) <= mid);
                c += (ub[i].z == T && (cb + 2) <= mid);
                c += (ub[i].w == T && (cb + 3) <= mid);
            }
            #pragma unroll
            for (int d = 32; d; d >>= 1) c += __shfl_xor(c, d);
            if (lane == 0) atomicAdd(&s_cnt, (unsigned)c);
            __syncthreads();
            if (s_cnt >= (unsigned)need) hiC = mid; else loC = mid + 1;
        }
        cstar = loC;
    }

    // ---- Pass 3: compose + non-temporal write, straight from registers.
    // accept(u, col) = u > T  ||  (u == T && col <= cstar). No bitmap, no mark. ----
    #pragma unroll
    for (int i = 0; i < NV; ++i) {
        const unsigned cb = (unsigned)(i * TPB + tid) * 4u;
        const unsigned u0 = ub[i].x, u1 = ub[i].y, u2 = ub[i].z, u3 = ub[i].w;
        fvec4 o;
        o.x = (u0 > T || (u0 == T && (cb + 0) <= cstar)) ? __uint_as_float(u0) : 0.f;
        o.y = (u1 > T || (u1 == T && (cb + 1) <= cstar)) ? __uint_as_float(u1) : 0.f;
        o.z = (u2 > T || (u2 == T && (cb + 2) <= cstar)) ? __uint_as_float(u2) : 0.f;
        o.w = (u3 > T || (u3 == T && (cb + 3) <= cstar)) ? __uint_as_float(u3) : 0.f;
        __builtin_nontemporal_store(o, &or4[i * TPB + tid]);
    }
}

extern "C" void kernel_launch(void* const* d_in, const int* in_sizes, int n_in,
                              void* d_out, int out_size, void* d_ws, size_t ws_size,
                              hipStream_t stream)
{
    const float* x   = (const float*)d_in[0];
    const int*   kp  = (const int*)d_in[1];
    float*       out = (float*)d_out;
    int rows = in_sizes[0] / COLS;               // 4096 for the reference shape
    topk_abs_kernel<<<rows, TPB, 0, stream>>>(x, kp, out);
}

// Round 9
// 99.973 us; speedup vs baseline: 2.8160x; 1.0425x over previous
//
#include <hip/hip_runtime.h>

#define COLS 16384
#define TPB  1024
#define NV   4                   // vec4 per thread (4*1024*4 = 16384 cols)
#define NW   (TPB / 64)          // 16 waves
#define NBIN 4096
#define CHK  (NBIN / TPB)        // 4 bins per thread in the scan
#define SH1  12

typedef unsigned uvec4 __attribute__((ext_vector_type(4)));
typedef float    fvec4 __attribute__((ext_vector_type(4)));

__global__ __launch_bounds__(TPB, 8) void topk_abs_kernel(
    const float* __restrict__ x, const int* __restrict__ kp,
    float* __restrict__ out)
{
    __shared__ int      hist[NBIN];     // 16 KB (fallback radix reuses [0,256))
    __shared__ int      wsum[NW];
    __shared__ unsigned s_cnt, s_max, s_total;
    __shared__ int      s_bin, s_G, s_eq;

    const int tid = threadIdx.x, lane = tid & 63, wid = tid >> 6;
    const int row = blockIdx.x;
    const int kin = kp[0];
    const unsigned kk = (unsigned)(kin < 0 ? 0 : (kin > COLS ? COLS : kin));

    const uvec4* __restrict__ xr  = (const uvec4*)(x + (size_t)row * COLS);
    fvec4* __restrict__       or4 = (fvec4*)(out + (size_t)row * COLS);

    // ---- Issue the row's loads; zero hist under their latency ----
    uvec4 ub[NV];
    #pragma unroll
    for (int i = 0; i < NV; ++i) ub[i] = __builtin_nontemporal_load(&xr[i * TPB + tid]);
    #pragma unroll
    for (int j = 0; j < CHK; ++j) hist[tid + j * TPB] = 0;
    __syncthreads();

    // ---- Pass 1: |x| mask + FIXED-bin histogram (u - T0) >> 12, clamp to 4095.
    // Bins cover |x| in [1.8, 7.2); N(0,1) tail past T0 ~7.2% -> ~1180 counts;
    // crossing bin holds ~0.3 elems on average. ----
    const unsigned T0 = 0x3FE66666u;    // bits(1.8f)
    #pragma unroll
    for (int i = 0; i < NV; ++i) {
        uvec4 t = ub[i] & 0x7FFFFFFFu;
        ub[i] = t;
        #define H1(u) { if ((u) >= T0) { unsigned b = ((u) - T0) >> SH1; \
                        b = b < (NBIN - 1) ? b : (NBIN - 1); atomicAdd(&hist[b], 1); } }
        H1(t.x) H1(t.y) H1(t.z) H1(t.w)
        #undef H1
    }
    __syncthreads();

    // ---- Descending suffix-scan over hist + crossing pick (both rounds) ----
    auto scan_pick = [&](int rank) {
        const int c  = (TPB - 1) - tid;          // tid 0 owns the TOP chunk
        const int b0 = c * CHK;
        int S = 0;
        #pragma unroll
        for (int j = 0; j < CHK; ++j) S += hist[b0 + j];
        int P = S;
        #pragma unroll
        for (int d = 1; d < 64; d <<= 1) { int t = __shfl_up(P, d); if (lane >= d) P += t; }
        if (lane == 63) wsum[wid] = P;
        __syncthreads();
        for (int w = 0; w < wid; ++w) P += wsum[w];
        const int above = P - S;                 // count strictly above this chunk
        if (P >= rank && above < rank) {         // unique crossing chunk
            int cum = above;
            #pragma unroll
            for (int j = CHK - 1; j >= 0; --j) {
                int h = hist[b0 + j], prev = cum;
                cum += h;
                if (cum >= rank && prev < rank) { s_bin = b0 + j; s_G = prev; s_eq = h; }
            }
        }
        if (tid == TPB - 1) s_total = (unsigned)P;   // chunk 0 inclusive = total
        __syncthreads();
    };

    unsigned T = 0xFFFFFFFFu;                    // kk==0 -> accept nothing
    int need = 0, eq = 0;
    if (kk > 0) {
        scan_pick((int)kk);
        const unsigned cnt = s_total;
        const int B1 = s_bin, G1 = s_G, E1 = s_eq;   // valid iff cnt >= kk
        bool handled = false;
        if (cnt == kk) { T = T0; need = 0; eq = 0; handled = true; }
        else if (cnt > kk && B1 < NBIN - 1) {
            if (G1 + E1 == (int)kk) {
                // rank boundary == bin floor: accept everything >= A1, skip pass 2
                T = T0 + ((unsigned)B1 << SH1); need = 0; eq = 0; handled = true;
            } else {
                // ---- Pass 2: exact select inside bin B1 (window 4096 keys) ----
                const unsigned A1 = T0 + ((unsigned)B1 << SH1);
                const int r1 = (int)kk - G1;
                #pragma unroll
                for (int j = 0; j < CHK; ++j) hist[tid + j * TPB] = 0;
                __syncthreads();
                #pragma unroll
                for (int i = 0; i < NV; ++i) {
                    #define H2(u) { unsigned d = (u) - A1; if (d < (unsigned)NBIN) atomicAdd(&hist[d], 1); }
                    H2(ub[i].x) H2(ub[i].y) H2(ub[i].z) H2(ub[i].w)
                    #undef H2
                }
                __syncthreads();
                scan_pick(r1);
                T = A1 + (unsigned)s_bin; need = r1 - s_G; eq = s_eq;
                handled = true;
            }
        }
        if (!handled) {
            // ---- Rare fallback (cnt < kk, or boundary in clamp bin):
            // bisection + adaptive 256-bin radix from registers. ----
            if (tid == 0) s_max = 0u;
            __syncthreads();
            unsigned lmax = 0u;
            #pragma unroll
            for (int i = 0; i < NV; ++i)
                lmax = max(lmax, max(max(ub[i].x, ub[i].y), max(ub[i].z, ub[i].w)));
            #pragma unroll
            for (int d = 32; d; d >>= 1) lmax = max(lmax, (unsigned)__shfl_xor((int)lmax, d));
            if (lane == 0) atomicMax(&s_max, lmax);
            __syncthreads();
            const unsigned smax = s_max;

            auto count_ge = [&](unsigned Tq) -> unsigned {
                __syncthreads();
                if (tid == 0) s_cnt = 0;
                __syncthreads();
                int c = 0;
                #pragma unroll
                for (int i = 0; i < NV; ++i)
                    c += (ub[i].x >= Tq) + (ub[i].y >= Tq) + (ub[i].z >= Tq) + (ub[i].w >= Tq);
                #pragma unroll
                for (int d = 32; d; d >>= 1) c += __shfl_xor(c, d);
                if (lane == 0) atomicAdd(&s_cnt, (unsigned)c);
                __syncthreads();
                return s_cnt;
            };

            unsigned T0f = T0, cntf = cnt;
            if (cntf < kk) {                     // lower the threshold exactly
                unsigned lo = 0u, hi = T0;
                while (hi - lo > 1u) {
                    unsigned mid = lo + ((hi - lo) >> 1);
                    if (count_ge(mid) >= kk) lo = mid; else hi = mid;
                }
                T0f = lo;
                cntf = count_ge(T0f);
            }
            if (cntf == kk)       { T = T0f; need = 0; eq = 0; }
            else if (smax == T0f) { T = T0f; eq = (int)cntf; need = (int)kk; }
            else {
                const unsigned range = smax - T0f;
                const int topbit = 31 - __clz(range);
                int sh = topbit - 7; if (sh < 0) sh = 0;
                unsigned A = T0f;
                unsigned W = (topbit >= 31) ? 0xFFFFFFFFu : (1u << (topbit + 1));
                int r = (int)kk;
                for (;;) {
                    if (tid < 256) hist[tid] = 0;
                    __syncthreads();
                    #pragma unroll
                    for (int i = 0; i < NV; ++i) {
                        #define HR(u) { if ((u) >= A && ((u) - A) < W) atomicAdd(&hist[((u) - A) >> sh], 1); }
                        HR(ub[i].x) HR(ub[i].y) HR(ub[i].z) HR(ub[i].w)
                        #undef HR
                    }
                    __syncthreads();
                    int bin = 0, val = 0, s = 0;
                    if (tid < 256) {
                        bin = 255 - tid;
                        val = hist[bin];
                        s = val;
                        #pragma unroll
                        for (int d = 1; d < 64; d <<= 1) { int t = __shfl_up(s, d); if (lane >= d) s += t; }
                        if (lane == 63) wsum[wid] = s;
                    }
                    __syncthreads();
                    if (tid < 256) {
                        for (int w = 0; w < wid; ++w) s += wsum[w];
                        if (s >= r && (s - val) < r) { s_bin = bin; s_G = s - val; if (sh == 0) s_eq = val; }
                    }
                    __syncthreads();
                    A += ((unsigned)s_bin) << sh;
                    W = 1u << sh;
                    r -= s_G;
                    if (sh == 0) break;
                    sh = (sh >= 8) ? sh - 8 : 0;
                }
                T = A; need = r; eq = s_eq;
            }
        }
    }

    // ---- Boundary tie (need != eq): among u==T accept the `need` lowest
    // columns; bisect the cutoff column with register-direct counts. ----
    unsigned cstar = COLS - 1;                   // default: accept all equals
    if (kk > 0 && need != eq) {
        unsigned loC = 0, hiC = COLS - 1;
        while (loC < hiC) {
            unsigned mid = (loC + hiC) >> 1;
            __syncthreads();
            if (tid == 0) s_cnt = 0;
            __syncthreads();
            int c = 0;
            #pragma unroll
            for (int i = 0; i < NV; ++i) {
                const unsigned cb = (unsigned)(i * TPB + tid) * 4u;
                c += (ub[i].x == T && (cb + 0) <= mid);
                c += (ub[i].y == T && (cb + 1) <= mid);
                c += (ub[i].z == T && (cb + 2) <= mid);
                c += (ub[i].w == T && (cb + 3) <= mid);
            }
            #pragma unroll
            for (int d = 32; d; d >>= 1) c += __shfl_xor(c, d);
            if (lane == 0) atomicAdd(&s_cnt, (unsigned)c);
            __syncthreads();
            if (s_cnt >= (unsigned)need) hiC = mid; else loC = mid + 1;
        }
        cstar = loC;
    }

    // ---- Pass 3: compose + non-temporal write, straight from registers.
    // accept(u, col) = u > T || (u == T && col <= cstar). ----
    #pragma unroll
    for (int i = 0; i < NV; ++i) {
        const unsigned cb = (unsigned)(i * TPB + tid) * 4u;
        const unsigned u0 = ub[i].x, u1 = ub[i].y, u2 = ub[i].z, u3 = ub[i].w;
        fvec4 o;
        o.x = (u0 > T || (u0 == T && (cb + 0) <= cstar)) ? __uint_as_float(u0) : 0.f;
        o.y = (u1 > T || (u1 == T && (cb + 1) <= cstar)) ? __uint_as_float(u1) : 0.f;
        o.z = (u2 > T || (u2 == T && (cb + 2) <= cstar)) ? __uint_as_float(u2) : 0.f;
        o.w = (u3 > T || (u3 == T && (cb + 3) <= cstar)) ? __uint_as_float(u3) : 0.f;
        __builtin_nontemporal_store(o, &or4[i * TPB + tid]);
    }
}

extern "C" void kernel_launch(void* const* d_in, const int* in_sizes, int n_in,
                              void* d_out, int out_size, void* d_ws, size_t ws_size,
                              hipStream_t stream)
{
    const float* x   = (const float*)d_in[0];
    const int*   kp  = (const int*)d_in[1];
    float*       out = (float*)d_out;
    int rows = in_sizes[0] / COLS;               // 4096 for the reference shape
    topk_abs_kernel<<<rows, TPB, 0, stream>>>(x, kp, out);
}